// Round 15
// baseline (2300.642 us; speedup 1.0000x reference)
//
#include <hip/hip_runtime.h>
#include <math.h>

typedef unsigned short u16;
typedef __bf16 bf16x8_t __attribute__((ext_vector_type(8)));
typedef u16 u16x8 __attribute__((ext_vector_type(8)));
typedef float f32x4 __attribute__((ext_vector_type(4)));

#define CBATCH 4
#define CN 577
#define CNP 576
#define CD 768
#define CH 12
#define CHD 64
#define CL 12
#define CMLP 3072
#define CVP 640                /* padded kv length for V */
#define CROWS (CBATCH*CN)      /* 2308 */
#define CROWSP 2432            /* padded row count for staged bufs (19*128) */
#define CNN2 332929            /* 577*577 */
#define CBH (CBATCH*CH)        /* 48 */
#define CSKP 2                 /* split-K for proj */
#define CSKF 2                 /* split-K for fc2 */
#define CMT2 19                /* ceil(2308/128) M-tiles (128-row) */
#define CRTP 2304              /* padded NUM_REL (2212 -> 2304) */

__device__ __forceinline__ float b2f(u16 u){
  unsigned x = ((unsigned)u) << 16;
  return __builtin_bit_cast(float, x);
}
__device__ __forceinline__ u16 f2b(float f){
  unsigned x = __builtin_bit_cast(unsigned, f);
  unsigned r = x + 0x7fffu + ((x >> 16) & 1u);
  return (u16)(r >> 16);
}

__device__ __forceinline__ f32x4 MFMA(u16x8 a, u16x8 b, f32x4 c){
  return __builtin_amdgcn_mfma_f32_16x16x32_bf16(
      __builtin_bit_cast(bf16x8_t, a), __builtin_bit_cast(bf16x8_t, b), c, 0, 0, 0);
}

__device__ __forceinline__ void gl_lds16(const u16* g, u16* l){
  __builtin_amdgcn_global_load_lds(
      (const __attribute__((address_space(1))) unsigned int*)g,
      (__attribute__((address_space(3))) unsigned int*)l, 16, 0, 0);
}

// bijective XCD chunk (m204)
__device__ __forceinline__ int xcd_chunk(int o, int nwg){
  int q8 = nwg >> 3, r8 = nwg & 7;
  int xcd = o & 7, sl = o >> 3;
  return (xcd < r8 ? xcd*(q8+1) : r8*(q8+1) + (xcd - r8)*q8) + sl;
}

// ---------------- small kernels ----------------

__global__ void cvt_kernel(const float* __restrict__ src, u16* __restrict__ dst, int n){
  int i = (blockIdx.x * 256 + threadIdx.x) * 4;
  if(i < n){
    float4 v = *reinterpret_cast<const float4*>(src + i);
    ushort4 o;
    o.x = f2b(v.x); o.y = f2b(v.y); o.z = f2b(v.z); o.w = f2b(v.w);
    *reinterpret_cast<ushort4*>(dst + i) = o;
  }
}

__global__ void zero_kernel(u16* __restrict__ p, int n){
  int i = (blockIdx.x * 256 + threadIdx.x) * 8;
  if(i < n){
    u16x8 z = {0,0,0,0,0,0,0,0};
    *reinterpret_cast<u16x8*>(p + i) = z;
  }
}

__global__ void im2col_kernel(const float* __restrict__ x, u16* __restrict__ out){
  int id = blockIdx.x * 256 + threadIdx.x;
  if(id >= 2304*768) return;
  int col = id % 768, row = id / 768;
  int b = row / 576, p = row % 576;
  int gy = p / 24, gx = p % 24;
  int c = col >> 8, rem = col & 255, py = rem >> 4, px = rem & 15;
  float v = x[(((long)(b*3 + c)*384) + gy*16 + py)*384 + gx*16 + px];
  out[id] = f2b(v);
}

__global__ void clspos_kernel(const float* __restrict__ cls, const float* __restrict__ pos,
                              float* __restrict__ h){
  int id = blockIdx.x * 256 + threadIdx.x;
  if(id < CBATCH*CD){
    int b = id / CD, d = id % CD;
    h[(long)b*CN*CD + d] = cls[d] + pos[d];
  }
}

// plain LayerNorm over 768 cols; one block per row.
template<bool BF16OUT>
__global__ void ln_kernel(const float* __restrict__ x, const float* __restrict__ w,
                          const float* __restrict__ bsh, u16* __restrict__ yb,
                          float* __restrict__ yf){
  int r = blockIdx.x;
  int tid = threadIdx.x;
  const float* px = x + (long)r*CD;
  float v0 = px[tid], v1 = px[tid+256], v2 = px[tid+512];
  __shared__ float red[4];
  float s = v0 + v1 + v2;
  #pragma unroll
  for(int m=1;m<64;m<<=1) s += __shfl_xor(s, m);
  if((tid & 63) == 0) red[tid>>6] = s;
  __syncthreads();
  s = red[0]+red[1]+red[2]+red[3];
  float mean = s * (1.0f/768.0f);
  float d0 = v0-mean, d1 = v1-mean, d2 = v2-mean;
  float s2 = d0*d0 + d1*d1 + d2*d2;
  __syncthreads();
  #pragma unroll
  for(int m=1;m<64;m<<=1) s2 += __shfl_xor(s2, m);
  if((tid & 63) == 0) red[tid>>6] = s2;
  __syncthreads();
  s2 = red[0]+red[1]+red[2]+red[3];
  float rs = rsqrtf(s2*(1.0f/768.0f) + 1e-6f);
  float o0 = d0*rs*w[tid]     + bsh[tid];
  float o1 = d1*rs*w[tid+256] + bsh[tid+256];
  float o2 = d2*rs*w[tid+512] + bsh[tid+512];
  if(BF16OUT){
    yb[(long)r*CD + tid]     = f2b(o0);
    yb[(long)r*CD + tid+256] = f2b(o1);
    yb[(long)r*CD + tid+512] = f2b(o2);
  } else {
    yf[(long)r*CD + tid]     = o0;
    yf[(long)r*CD + tid+256] = o1;
    yf[(long)r*CD + tid+512] = o2;
  }
}

// fused: h += sum_{NSK}(part) + bias, then (optionally) y = LN(h)*w+b (bf16)
template<bool DOLN, int NSK>
__global__ void resid_ln_kernel(float* __restrict__ h, const float* __restrict__ part,
    const float* __restrict__ bias, const float* __restrict__ w,
    const float* __restrict__ bsh, u16* __restrict__ y){
  int r = blockIdx.x, tid = threadIdx.x;
  float v[3];
  #pragma unroll
  for(int j=0;j<3;j++){
    int c = tid + j*256;
    float t = h[(long)r*CD + c] + bias[c];
    #pragma unroll
    for(int sk=0; sk<NSK; sk++) t += part[((long)sk*CROWS + r)*CD + c];
    v[j] = t;
    h[(long)r*CD + c] = t;
  }
  if constexpr(DOLN){
    __shared__ float red[4];
    float s = v[0]+v[1]+v[2];
    #pragma unroll
    for(int m=1;m<64;m<<=1) s += __shfl_xor(s, m);
    if((tid & 63) == 0) red[tid>>6] = s;
    __syncthreads();
    s = red[0]+red[1]+red[2]+red[3];
    float mean = s * (1.0f/768.0f);
    float d0=v[0]-mean, d1=v[1]-mean, d2=v[2]-mean;
    float s2 = d0*d0+d1*d1+d2*d2;
    __syncthreads();
    #pragma unroll
    for(int m=1;m<64;m<<=1) s2 += __shfl_xor(s2, m);
    if((tid & 63) == 0) red[tid>>6] = s2;
    __syncthreads();
    s2 = red[0]+red[1]+red[2]+red[3];
    float rs = rsqrtf(s2*(1.0f/768.0f) + 1e-6f);
    y[(long)r*CD + tid]     = f2b(d0*rs*w[tid]     + bsh[tid]);
    y[(long)r*CD + tid+256] = f2b(d1*rs*w[tid+256] + bsh[tid+256]);
    y[(long)r*CD + tid+512] = f2b(d2*rs*w[tid+512] + bsh[tid+512]);
  }
}

// rtT build: rtT[l][h][rel] = bf16(rtab[l][rel][h]); rel padded to 2304 with 0.
__global__ void rtT_kernel(const float* __restrict__ rtab, u16* __restrict__ rtT){
  int rel = blockIdx.x * 256 + threadIdx.x;
  int l = blockIdx.y;
  if(rel >= CRTP) return;
  const float* row = rtab + ((long)l*2212 + rel)*12;
  #pragma unroll
  for(int hh=0; hh<12; hh++){
    u16 v = 0;
    if(rel < 2212) v = f2b(row[hh]);
    rtT[((long)l*12 + hh)*CRTP + rel] = v;
  }
}

// ---------------- fused flash attention (R14, passing) ----------------
__global__ __launch_bounds__(256) void attn_kernel(
    const u16* __restrict__ q, const u16* __restrict__ k,
    const u16* __restrict__ vt, const u16* __restrict__ rtT,
    u16* __restrict__ o_){
  __shared__ __align__(16) u16 lK[2][64*64];
  __shared__ __align__(16) u16 lV[2][64*64];
  __shared__ u16 pt[4][16*72];
  __shared__ __align__(16) u16 rtc[CRTP];
  const int tid = threadIdx.x, lane = tid & 63, wv = tid >> 6;
  const int i15 = lane & 15, g4 = lane >> 4;
  const int o = blockIdx.y * 10 + blockIdx.x;   // bh-major linear id (480 = 8*60)
  const int cm = xcd_chunk(o, 480);
  const int bh = cm / 10, qt = cm % 10;
  const int b = bh / CH, hh = cm % 10 == qt ? (bh % CH) : (bh % CH);
  const int qrow0 = qt*64 + wv*16;
  const u16* qp = q + ((long)bh*CN + qrow0 + i15)*CHD + g4*8;
  u16x8 qa0 = *reinterpret_cast<const u16x8*>(qp);
  u16x8 qa1 = *reinterpret_cast<const u16x8*>(qp + 32);
  const u16* kbase = k + (long)bh*CN*CHD;
  const u16* vbase = vt + (long)bh*CHD*CVP;

  for(int i = tid; i < CRTP/8; i += 256)
    *reinterpret_cast<u16x8*>(&rtc[i*8]) = *reinterpret_cast<const u16x8*>(rtT + (long)hh*CRTP + i*8);
  __syncthreads();

  int qbase[4];
  bool qz[4];
  #pragma unroll
  for(int r=0;r<4;r++){
    int qr = qrow0 + g4*4 + r; if(qr > 576) qr = 576;
    qz[r] = (qr == 0);
    int pq = qr - 1; if(pq < 0) pq = 0;
    int iq = pq / 24, jq = pq - iq*24;
    qbase[r] = (iq + 23)*47 + (jq + 23);
  }

  const int srow = wv*16 + (lane>>3);
  const int scol = (((lane&7) ^ ((lane>>3)&7)))*8;
  const int sdst = wv*16*64;
  const int rsw = i15 & 7;

  f32x4 po[4];
  float m[4], l[4];
  #pragma unroll
  for(int i=0;i<4;i++){ po[i]=(f32x4){0,0,0,0}; m[i]=-3.0e38f; l[i]=0.0f; }

  auto STAGE = [&](int t, int buf){
    const int kv0 = t*64;
    const u16* ks = kbase + ((long)(kv0 + srow))*CHD + scol;
    const u16* vs = vbase + ((long)srow)*CVP + kv0 + scol;
    gl_lds16(ks,          &lK[buf][sdst]);
    gl_lds16(ks + 8*CHD,  &lK[buf][sdst + 8*64]);
    gl_lds16(vs,          &lV[buf][sdst]);
    gl_lds16(vs + 8*CVP,  &lV[buf][sdst + 8*64]);
  };

  STAGE(0, 0);
  for(int t=0;t<10;t++){
    const int kv0 = t*64;
    int idxr[4][4];
    #pragma unroll
    for(int fc=0;fc<4;fc++){
      int kvc = kv0 + fc*16 + i15; if(kvc > 576) kvc = 576;
      bool kz = (kvc == 0);
      int pk = kvc - 1; if(pk < 0) pk = 0;
      int ik = pk / 24, jk = pk - ik*24;
      int ksub = ik*47 + jk;
      #pragma unroll
      for(int r=0;r<4;r++){
        int idx = qbase[r] - ksub;
        if(qz[r]) idx = 2209;
        if(kz)    idx = qz[r] ? 2211 : 2210;
        idxr[fc][r] = idx;
      }
    }
    if(t+1 < 10){
      STAGE(t+1, (t+1)&1);
      asm volatile("s_waitcnt vmcnt(4) lgkmcnt(0)" ::: "memory");
    } else {
      asm volatile("s_waitcnt vmcnt(0) lgkmcnt(0)" ::: "memory");
    }
    __builtin_amdgcn_s_barrier();
    const int buf = t&1;
    f32x4 sa[4];
    __builtin_amdgcn_s_setprio(1);
    #pragma unroll
    for(int fc=0;fc<4;fc++){
      const int rb = (fc*16+i15)*64;
      u16x8 k0 = *reinterpret_cast<const u16x8*>(&lK[buf][rb + ((g4 ^ rsw)<<3)]);
      u16x8 k1 = *reinterpret_cast<const u16x8*>(&lK[buf][rb + (((4|g4) ^ rsw)<<3)]);
      f32x4 z = (f32x4){0,0,0,0};
      z = MFMA(qa0, k0, z);
      z = MFMA(qa1, k1, z);
      sa[fc] = z;
    }
    __builtin_amdgcn_s_setprio(0);
    float s[4][4];
    #pragma unroll
    for(int fc=0;fc<4;fc++){
      int kvc = kv0 + fc*16 + i15;
      bool valid = kvc < CN;
      #pragma unroll
      for(int r=0;r<4;r++){
        float bias = b2f(rtc[idxr[fc][r]]);
        s[fc][r] = valid ? (sa[fc][r] + bias) : -1e30f;
      }
    }
    float tm[4], ts[4], sc[4];
    #pragma unroll
    for(int r=0;r<4;r++)
      tm[r] = fmaxf(fmaxf(s[0][r],s[1][r]), fmaxf(s[2][r],s[3][r]));
    #pragma unroll
    for(int msk=1; msk<16; msk<<=1)
      #pragma unroll
      for(int r=0;r<4;r++)
        tm[r] = fmaxf(tm[r], __shfl_xor(tm[r], msk));
    #pragma unroll
    for(int r=0;r<4;r++){
      float mn = fmaxf(m[r], tm[r]);
      sc[r] = exp2f((m[r]-mn)*1.4426950408889634f);
      m[r] = mn;
      ts[r] = 0.f;
    }
    #pragma unroll
    for(int fc=0;fc<4;fc++)
      #pragma unroll
      for(int r=0;r<4;r++){
        float p = exp2f((s[fc][r]-m[r])*1.4426950408889634f);
        s[fc][r] = p; ts[r] += p;
      }
    #pragma unroll
    for(int msk=1; msk<16; msk<<=1)
      #pragma unroll
      for(int r=0;r<4;r++)
        ts[r] += __shfl_xor(ts[r], msk);
    #pragma unroll
    for(int r=0;r<4;r++) l[r] = l[r]*sc[r] + ts[r];
    #pragma unroll
    for(int d=0; d<4; d++)
      #pragma unroll
      for(int r=0;r<4;r++) po[d][r] *= sc[r];
    #pragma unroll
    for(int fc=0;fc<4;fc++)
      #pragma unroll
      for(int r=0;r<4;r++)
        pt[wv][(g4*4+r)*72 + fc*16 + i15] = f2b(s[fc][r]);
    u16x8 pa0 = *reinterpret_cast<const u16x8*>(&pt[wv][i15*72 + g4*8]);
    u16x8 pa1 = *reinterpret_cast<const u16x8*>(&pt[wv][i15*72 + 32 + g4*8]);
    __builtin_amdgcn_s_setprio(1);
    #pragma unroll
    for(int d=0; d<4; d++){
      const int rb = (d*16+i15)*64;
      u16x8 v0 = *reinterpret_cast<const u16x8*>(&lV[buf][rb + ((g4 ^ rsw)<<3)]);
      u16x8 v1 = *reinterpret_cast<const u16x8*>(&lV[buf][rb + (((4|g4) ^ rsw)<<3)]);
      po[d] = MFMA(pa0, v0, po[d]);
      po[d] = MFMA(pa1, v1, po[d]);
    }
    __builtin_amdgcn_s_setprio(0);
    __builtin_amdgcn_s_barrier();
  }
  #pragma unroll
  for(int d=0; d<4; d++)
    #pragma unroll
    for(int r=0;r<4;r++){
      int qr = qrow0 + g4*4 + r;
      if(qr < CN)
        o_[((long)(b*CN + qr))*CD + hh*CHD + d*16 + i15] = f2b(po[d][r] / l[r]);
    }
}

__global__ void pool_kernel(const float* __restrict__ h, float* __restrict__ pooled){
  int id = blockIdx.x * 256 + threadIdx.x;
  if(id >= CBATCH*CD) return;
  int b = id / CD, d = id % CD;
  const float* p = h + ((long)b*CN + 1)*CD + d;
  float s = 0.0f;
  for(int i=0;i<CNP;i++) s += p[(long)i*CD];
  pooled[id] = s * (1.0f/576.0f);
}

__global__ void head_kernel(const float* __restrict__ xn, const float* __restrict__ hw,
                            const float* __restrict__ hb, float* __restrict__ out){
  int nc = blockIdx.x;
  int tid = threadIdx.x;
  const float* wr = hw + (long)nc*CD;
  float w0 = wr[tid], w1 = wr[tid+256], w2 = wr[tid+512];
  __shared__ float red[4];
  for(int b=0;b<CBATCH;b++){
    const float* xr = xn + (long)b*CD;
    float s = w0*xr[tid] + w1*xr[tid+256] + w2*xr[tid+512];
    #pragma unroll
    for(int m=1;m<64;m<<=1) s += __shfl_xor(s, m);
    if((tid&63)==0) red[tid>>6] = s;
    __syncthreads();
    if(tid==0) out[b*1000 + nc] = red[0]+red[1]+red[2]+red[3] + hb[nc];
    __syncthreads();
  }
}

// ---------------- GEMM: 128x128 tile, 4 waves each 64x64 (16 MFMA/step) -----
// Swizzled LDS (2-way, free), 3-slot counted-vmcnt pipeline (STAGE = 4 loads,
// vmcnt(4) mid-loop), setprio around MFMA cluster. 48 KB LDS -> 3 blocks/CU.

struct EpiArgs {
  float* hres;
  u16* outb;
  const float* bias;
  const float* pos;
  const float* qb;
  const float* vb;
  u16* q;
  u16* k;
  u16* vt;
  float* part;
};

enum { EPI_PATCH=0, EPI_QKV, EPI_GELU, EPI_PART };

template<int EPI>
__global__ __launch_bounds__(256,3) void gemm5(const u16* __restrict__ A, const u16* __restrict__ Bm,
    int M, int N, int K, int lda, int ldb, EpiArgs e){
  __shared__ __align__(16) u16 lA[3][128*32];
  __shared__ __align__(16) u16 lB[3][128*32];
  const int tid  = threadIdx.x;
  const int lane = tid & 63;
  const int wv   = tid >> 6;

  const int gx = gridDim.x, gy = gridDim.y;
  const int o = blockIdx.y * gx + blockIdx.x;
  const int cm = xcd_chunk(o, gx*gy);          // column-major tile index
  const int bn = (cm / gy) * 128;
  const int bm = (cm % gy) * 128;

  const int z  = blockIdx.z;
  A  += (long)z * K;
  Bm += (long)z * K;

  const int srow = wv*16 + (lane>>2);
  const int wsz = ((lane&3) ^ ((lane>>3)&3)) * 8;
  const u16* Asb = A  + (long)(bm + srow)*lda + wsz;
  const u16* Bsb = Bm + (long)(bn + srow)*ldb + wsz;
  const int ldst = wv*16*32;

  const int rbase = (wv>>1)*64;      // 0 or 64 within 128-row tile
  const int cbase = (wv&1)*64;       // 0 or 64 within 128-col tile
  const int i15 = lane & 15;
  const int k8off = (((lane>>4) ^ ((i15>>1)&3))) << 3;

  f32x4 acc[4][4];
  #pragma unroll
  for(int i=0;i<4;i++)
    #pragma unroll
    for(int j=0;j<4;j++)
      acc[i][j] = (f32x4){0.0f,0.0f,0.0f,0.0f};

  const int nkt = K >> 5;

  auto STAGE = [&](int kt, int slot){
    const u16* Ak = Asb + (long)kt*32;
    const u16* Bk = Bsb + (long)kt*32;
    gl_lds16(Ak,          &lA[slot][ldst]);
    gl_lds16(Ak + 64*lda, &lA[slot][ldst + 64*32]);
    gl_lds16(Bk,          &lB[slot][ldst]);
    gl_lds16(Bk + 64*ldb, &lB[slot][ldst + 64*32]);
  };

  STAGE(0, 0);
  if(nkt > 1) STAGE(1, 1);

  for(int kt=0; kt<nkt; kt++){
    if(kt+1 < nkt) asm volatile("s_waitcnt vmcnt(4) lgkmcnt(0)" ::: "memory");
    else           asm volatile("s_waitcnt vmcnt(0) lgkmcnt(0)" ::: "memory");
    __builtin_amdgcn_s_barrier();
    int nxt2 = kt + 2;
    if(nxt2 < nkt){ int sl = nxt2 % 3; STAGE(nxt2, sl); }
    const int cur = kt % 3;
    u16x8 af[4], bfr[4];
    #pragma unroll
    for(int f=0; f<4; f++){
      af[f]  = *reinterpret_cast<const u16x8*>(&lA[cur][(rbase + f*16 + i15)*32 + k8off]);
      bfr[f] = *reinterpret_cast<const u16x8*>(&lB[cur][(cbase + f*16 + i15)*32 + k8off]);
    }
    __builtin_amdgcn_s_setprio(1);
    #pragma unroll
    for(int fr=0; fr<4; fr++)
      #pragma unroll
      for(int fc=0; fc<4; fc++)
        acc[fr][fc] = MFMA(af[fr], bfr[fc], acc[fr][fc]);
    __builtin_amdgcn_s_setprio(0);
  }

  // epilogue: C/D layout col=lane&15, row=(lane>>4)*4+r
  #pragma unroll
  for(int fr=0; fr<4; fr++){
    #pragma unroll
    for(int fc=0; fc<4; fc++){
      #pragma unroll
      for(int r=0;r<4;r++){
        int row = bm + rbase + fr*16 + ((lane>>4)<<2) + r;
        int col = bn + cbase + fc*16 + i15;
        if(row >= M || col >= N) continue;
        float v = acc[fr][fc][r];
        if constexpr(EPI == EPI_PATCH){
          int b = row/576, p = row%576;
          e.hres[((long)b*CN + 1 + p)*CD + col] = v + e.bias[col] + e.pos[(long)(1+p)*CD + col];
        } else if constexpr(EPI == EPI_QKV){
          int b = row/CN, n = row%CN;
          if(col < 768){
            int hh = col>>6, d = col&63;
            e.q[(((long)(b*CH+hh))*CN + n)*CHD + d] = f2b((v + e.qb[col]) * 0.125f);
          } else if(col < 1536){
            int c2 = col-768; int hh = c2>>6, d = c2&63;
            e.k[(((long)(b*CH+hh))*CN + n)*CHD + d] = f2b(v);
          } else {
            int c2 = col-1536; int hh = c2>>6, d = c2&63;
            e.vt[(((long)(b*CH+hh))*CHD + d)*CVP + n] = f2b(v + e.vb[c2]);
          }
        } else if constexpr(EPI == EPI_GELU){
          float t = v + e.bias[col];
          e.outb[(long)row*N + col] = f2b(t * 0.5f * (1.0f + erff(t*0.70710678118f)));
        } else { // EPI_PART: f32 partial, bias added in resid_ln
          e.part[((long)z*CROWS + row)*CD + col] = v;
        }
      }
    }
  }
}

// ---------------- host ----------------

extern "C" void kernel_launch(void* const* d_in, const int* in_sizes, int n_in,
                              void* d_out, int out_size, void* d_ws, size_t ws_size,
                              hipStream_t stream){
  const float* x        = (const float*)d_in[0];
  const float* patch_w  = (const float*)d_in[1];
  const float* patch_b  = (const float*)d_in[2];
  const float* cls_tok  = (const float*)d_in[3];
  const float* pos_emb  = (const float*)d_in[4];
  const float* ln1_w    = (const float*)d_in[5];
  const float* ln1_b    = (const float*)d_in[6];
  const float* qkv_w    = (const float*)d_in[7];
  const float* q_bias   = (const float*)d_in[8];
  const float* v_bias   = (const float*)d_in[9];
  const float* proj_w   = (const float*)d_in[10];
  const float* proj_b   = (const float*)d_in[11];
  const float* ln2_w    = (const float*)d_in[12];
  const float* ln2_b    = (const float*)d_in[13];
  const float* fc1_w    = (const float*)d_in[14];
  const float* fc1_b    = (const float*)d_in[15];
  const float* fc2_w    = (const float*)d_in[16];
  const float* fc2_b    = (const float*)d_in[17];
  const float* rel_tab  = (const float*)d_in[18];
  const float* fcn_w    = (const float*)d_in[19];
  const float* fcn_b    = (const float*)d_in[20];
  const float* head_w   = (const float*)d_in[21];
  const float* head_b   = (const float*)d_in[22];
  float* out = (float*)d_out;
  char* ws = (char*)d_ws;

  size_t off = 0;
  auto alloc = [&](size_t bytes)->size_t{
    size_t o = off; off += (bytes + 255) & ~(size_t)255; return o;
  };
  const size_t OFF_H    = alloc((size_t)CROWS*CD*4);            // f32 residual
  const size_t OFF_Y    = alloc((size_t)CROWSP*CD*2);           // bf16 LN out
  const size_t OFF_Q    = alloc(((size_t)CBH*CN + 128)*CHD*2);
  const size_t OFF_K    = alloc(((size_t)CBH*CN + 128)*CHD*2);
  const size_t OFF_VT   = alloc((size_t)CBH*CHD*CVP*2);
  const size_t OFF_O    = alloc((size_t)CROWSP*CD*2);
  const size_t OFF_HID  = alloc((size_t)CROWSP*CMLP*2);         // also im2col A
  const size_t OFF_PART = alloc((size_t)4*CROWS*CD*4);          // split-K partials
  const size_t OFF_RTT  = alloc((size_t)CL*12*CRTP*2);          // rt columns (637 KB)
  const size_t OFF_WP0  = alloc((size_t)768*768*2);
  const size_t OFF_WQA  = alloc((size_t)CL*2304*768*2);
  const size_t OFF_WPA  = alloc((size_t)CL*768*768*2);
  const size_t OFF_W1A  = alloc((size_t)CL*3072*768*2);
  const size_t OFF_W2A  = alloc((size_t)CL*768*3072*2);
  const size_t OFF_PL   = alloc((size_t)CBATCH*CD*4);
  const size_t OFF_NM   = alloc((size_t)CBATCH*CD*4);
  (void)ws_size; (void)in_sizes; (void)n_in; (void)out_size;

  float* h      = (float*)(ws + OFF_H);
  u16*   y      = (u16*)(ws + OFF_Y);
  u16*   qb_    = (u16*)(ws + OFF_Q);
  u16*   kb_    = (u16*)(ws + OFF_K);
  u16*   vt_    = (u16*)(ws + OFF_VT);
  u16*   o_     = (u16*)(ws + OFF_O);
  u16*   hid    = (u16*)(ws + OFF_HID);
  float* part   = (float*)(ws + OFF_PART);
  u16*   rtT    = (u16*)(ws + OFF_RTT);
  u16*   wp0    = (u16*)(ws + OFF_WP0);
  u16*   wqA    = (u16*)(ws + OFF_WQA);
  u16*   wpA    = (u16*)(ws + OFF_WPA);
  u16*   w1A    = (u16*)(ws + OFF_W1A);
  u16*   w2A    = (u16*)(ws + OFF_W2A);
  float* pooled = (float*)(ws + OFF_PL);
  float* normed = (float*)(ws + OFF_NM);

  auto cvt = [&](const float* src, u16* dst, long n){
    cvt_kernel<<<dim3((unsigned)((n/4 + 255)/256)), dim3(256), 0, stream>>>(src, dst, (int)n);
  };

  // ---- upfront ----
  {
    int n = CBH*CHD*CVP;
    zero_kernel<<<dim3((n/8 + 255)/256), dim3(256), 0, stream>>>(vt_, n);
  }
  im2col_kernel<<<dim3((2304*768 + 255)/256), dim3(256), 0, stream>>>(x, hid);
  cvt(patch_w, wp0, 768*768);
  cvt(qkv_w,  wqA, (long)CL*2304*768);
  cvt(proj_w, wpA, (long)CL*768*768);
  cvt(fc1_w,  w1A, (long)CL*3072*768);
  cvt(fc2_w,  w2A, (long)CL*768*3072);
  rtT_kernel<<<dim3(CRTP/256, CL), dim3(256), 0, stream>>>(rel_tab, rtT);

  // ---- patch embed ----
  {
    EpiArgs e{}; e.hres = h; e.bias = patch_b; e.pos = pos_emb;
    gemm5<EPI_PATCH><<<dim3(6,18,1), dim3(256), 0, stream>>>(
        hid, wp0, 2304, 768, 768, 768, 768, e);
  }
  clspos_kernel<<<dim3(12), dim3(256), 0, stream>>>(cls_tok, pos_emb, h);

  // layer-0 LN1 (no pending partials)
  ln_kernel<true><<<dim3(CROWS), dim3(256), 0, stream>>>(
      h, ln1_w, ln1_b, y, nullptr);

  // ---- layers ----
  for(int l=0; l<CL; l++){
    { // qkv
      EpiArgs e{}; e.qb = q_bias + l*CD; e.vb = v_bias + l*CD;
      e.q = qb_; e.k = kb_; e.vt = vt_;
      gemm5<EPI_QKV><<<dim3(18,CMT2,1), dim3(256), 0, stream>>>(
          y, wqA + (long)l*2304*768, CROWS, 2304, 768, 768, 768, e);
    }
    attn_kernel<<<dim3(10, CBH), dim3(256), 0, stream>>>(
        qb_, kb_, vt_, rtT + (long)l*12*CRTP, o_);
    { // proj partials: split-K=2, K'=384
      EpiArgs e{}; e.part = part;
      gemm5<EPI_PART><<<dim3(6,CMT2,CSKP), dim3(256), 0, stream>>>(
          o_, wpA + (long)l*768*768, CROWS, 768, 768/CSKP, 768, 768, e);
    }
    // h += proj + pb ; y = LN2(h)
    resid_ln_kernel<true,CSKP><<<dim3(CROWS), dim3(256), 0, stream>>>(
        h, part, proj_b + l*CD, ln2_w + l*CD, ln2_b + l*CD, y);
    { // hid = gelu(y fc1^T + b1)
      EpiArgs e{}; e.outb = hid; e.bias = fc1_b + l*CMLP;
      gemm5<EPI_GELU><<<dim3(24,CMT2,1), dim3(256), 0, stream>>>(
          y, w1A + (long)l*3072*768, CROWS, 3072, 768, 768, 768, e);
    }
    { // fc2 partials: split-K=2, K'=1536
      EpiArgs e{}; e.part = part;
      gemm5<EPI_PART><<<dim3(6,CMT2,CSKF), dim3(256), 0, stream>>>(
          hid, w2A + (long)l*768*3072, CROWS, 768, 3072/CSKF, 3072, 3072, e);
    }
    if(l+1 < CL){
      // h += fc2 + b2 ; y = LN1_{l+1}(h)
      resid_ln_kernel<true,CSKF><<<dim3(CROWS), dim3(256), 0, stream>>>(
          h, part, fc2_b + l*CD, ln1_w + (l+1)*CD, ln1_b + (l+1)*CD, y);
    } else {
      resid_ln_kernel<false,CSKF><<<dim3(CROWS), dim3(256), 0, stream>>>(
          h, part, fc2_b + l*CD, nullptr, nullptr, nullptr);
    }
  }

  // ---- pool + fc_norm + head ----
  pool_kernel<<<dim3(12), dim3(256), 0, stream>>>(h, pooled);
  ln_kernel<false><<<dim3(CBATCH), dim3(256), 0, stream>>>(
      pooled, fcn_w, fcn_b, nullptr, normed);
  head_kernel<<<dim3(1000), dim3(256), 0, stream>>>(normed, head_w, head_b, out);
}

// Round 16
// 2013.748 us; speedup vs baseline: 1.1425x; 1.1425x over previous
//
#include <hip/hip_runtime.h>
#include <math.h>

typedef unsigned short u16;
typedef __bf16 bf16x8_t __attribute__((ext_vector_type(8)));
typedef u16 u16x8 __attribute__((ext_vector_type(8)));
typedef float f32x4 __attribute__((ext_vector_type(4)));

#define CBATCH 4
#define CN 577
#define CNP 576
#define CD 768
#define CH 12
#define CHD 64
#define CL 12
#define CMLP 3072
#define CVP 640                /* padded kv length for V */
#define CROWS (CBATCH*CN)      /* 2308 */
#define CROWSP 2432            /* padded row count for staged bufs */
#define CNN2 332929            /* 577*577 */
#define CBH (CBATCH*CH)        /* 48 */
#define CSKP 2                 /* split-K for proj */
#define CSKF 2                 /* split-K for fc2 */
#define CMT 37                 /* ceil(2308/64) M-tiles */
#define CRTP 2304              /* padded NUM_REL (2212 -> 2304) */

__device__ __forceinline__ float b2f(u16 u){
  unsigned x = ((unsigned)u) << 16;
  return __builtin_bit_cast(float, x);
}
__device__ __forceinline__ u16 f2b(float f){
  unsigned x = __builtin_bit_cast(unsigned, f);
  unsigned r = x + 0x7fffu + ((x >> 16) & 1u);
  return (u16)(r >> 16);
}

__device__ __forceinline__ f32x4 MFMA(u16x8 a, u16x8 b, f32x4 c){
  return __builtin_amdgcn_mfma_f32_16x16x32_bf16(
      __builtin_bit_cast(bf16x8_t, a), __builtin_bit_cast(bf16x8_t, b), c, 0, 0, 0);
}

__device__ __forceinline__ void gl_lds16(const u16* g, u16* l){
  __builtin_amdgcn_global_load_lds(
      (const __attribute__((address_space(1))) unsigned int*)g,
      (__attribute__((address_space(3))) unsigned int*)l, 16, 0, 0);
}

// bijective XCD chunk (m204)
__device__ __forceinline__ int xcd_chunk(int o, int nwg){
  int q8 = nwg >> 3, r8 = nwg & 7;
  int xcd = o & 7, sl = o >> 3;
  return (xcd < r8 ? xcd*(q8+1) : r8*(q8+1) + (xcd - r8)*q8) + sl;
}

// ---------------- small kernels ----------------

__global__ void cvt_kernel(const float* __restrict__ src, u16* __restrict__ dst, int n){
  int i = (blockIdx.x * 256 + threadIdx.x) * 4;
  if(i < n){
    float4 v = *reinterpret_cast<const float4*>(src + i);
    ushort4 o;
    o.x = f2b(v.x); o.y = f2b(v.y); o.z = f2b(v.z); o.w = f2b(v.w);
    *reinterpret_cast<ushort4*>(dst + i) = o;
  }
}

__global__ void zero_kernel(u16* __restrict__ p, int n){
  int i = (blockIdx.x * 256 + threadIdx.x) * 8;
  if(i < n){
    u16x8 z = {0,0,0,0,0,0,0,0};
    *reinterpret_cast<u16x8*>(p + i) = z;
  }
}

__global__ void im2col_kernel(const float* __restrict__ x, u16* __restrict__ out){
  int id = blockIdx.x * 256 + threadIdx.x;
  if(id >= 2304*768) return;
  int col = id % 768, row = id / 768;
  int b = row / 576, p = row % 576;
  int gy = p / 24, gx = p % 24;
  int c = col >> 8, rem = col & 255, py = rem >> 4, px = rem & 15;
  float v = x[(((long)(b*3 + c)*384) + gy*16 + py)*384 + gx*16 + px];
  out[id] = f2b(v);
}

__global__ void clspos_kernel(const float* __restrict__ cls, const float* __restrict__ pos,
                              float* __restrict__ h){
  int id = blockIdx.x * 256 + threadIdx.x;
  if(id < CBATCH*CD){
    int b = id / CD, d = id % CD;
    h[(long)b*CN*CD + d] = cls[d] + pos[d];
  }
}

// plain LayerNorm over 768 cols; one block per row.
template<bool BF16OUT>
__global__ void ln_kernel(const float* __restrict__ x, const float* __restrict__ w,
                          const float* __restrict__ bsh, u16* __restrict__ yb,
                          float* __restrict__ yf){
  int r = blockIdx.x;
  int tid = threadIdx.x;
  const float* px = x + (long)r*CD;
  float v0 = px[tid], v1 = px[tid+256], v2 = px[tid+512];
  __shared__ float red[4];
  float s = v0 + v1 + v2;
  #pragma unroll
  for(int m=1;m<64;m<<=1) s += __shfl_xor(s, m);
  if((tid & 63) == 0) red[tid>>6] = s;
  __syncthreads();
  s = red[0]+red[1]+red[2]+red[3];
  float mean = s * (1.0f/768.0f);
  float d0 = v0-mean, d1 = v1-mean, d2 = v2-mean;
  float s2 = d0*d0 + d1*d1 + d2*d2;
  __syncthreads();
  #pragma unroll
  for(int m=1;m<64;m<<=1) s2 += __shfl_xor(s2, m);
  if((tid & 63) == 0) red[tid>>6] = s2;
  __syncthreads();
  s2 = red[0]+red[1]+red[2]+red[3];
  float rs = rsqrtf(s2*(1.0f/768.0f) + 1e-6f);
  float o0 = d0*rs*w[tid]     + bsh[tid];
  float o1 = d1*rs*w[tid+256] + bsh[tid+256];
  float o2 = d2*rs*w[tid+512] + bsh[tid+512];
  if(BF16OUT){
    yb[(long)r*CD + tid]     = f2b(o0);
    yb[(long)r*CD + tid+256] = f2b(o1);
    yb[(long)r*CD + tid+512] = f2b(o2);
  } else {
    yf[(long)r*CD + tid]     = o0;
    yf[(long)r*CD + tid+256] = o1;
    yf[(long)r*CD + tid+512] = o2;
  }
}

// fused: h += sum_{NSK}(part) + bias, then (optionally) y = LN(h)*w+b (bf16)
template<bool DOLN, int NSK>
__global__ void resid_ln_kernel(float* __restrict__ h, const float* __restrict__ part,
    const float* __restrict__ bias, const float* __restrict__ w,
    const float* __restrict__ bsh, u16* __restrict__ y){
  int r = blockIdx.x, tid = threadIdx.x;
  float v[3];
  #pragma unroll
  for(int j=0;j<3;j++){
    int c = tid + j*256;
    float t = h[(long)r*CD + c] + bias[c];
    #pragma unroll
    for(int sk=0; sk<NSK; sk++) t += part[((long)sk*CROWS + r)*CD + c];
    v[j] = t;
    h[(long)r*CD + c] = t;
  }
  if constexpr(DOLN){
    __shared__ float red[4];
    float s = v[0]+v[1]+v[2];
    #pragma unroll
    for(int m=1;m<64;m<<=1) s += __shfl_xor(s, m);
    if((tid & 63) == 0) red[tid>>6] = s;
    __syncthreads();
    s = red[0]+red[1]+red[2]+red[3];
    float mean = s * (1.0f/768.0f);
    float d0=v[0]-mean, d1=v[1]-mean, d2=v[2]-mean;
    float s2 = d0*d0+d1*d1+d2*d2;
    __syncthreads();
    #pragma unroll
    for(int m=1;m<64;m<<=1) s2 += __shfl_xor(s2, m);
    if((tid & 63) == 0) red[tid>>6] = s2;
    __syncthreads();
    s2 = red[0]+red[1]+red[2]+red[3];
    float rs = rsqrtf(s2*(1.0f/768.0f) + 1e-6f);
    y[(long)r*CD + tid]     = f2b(d0*rs*w[tid]     + bsh[tid]);
    y[(long)r*CD + tid+256] = f2b(d1*rs*w[tid+256] + bsh[tid+256]);
    y[(long)r*CD + tid+512] = f2b(d2*rs*w[tid+512] + bsh[tid+512]);
  }
}

// rtT build: rtT[l][h][rel] = bf16(rtab[l][rel][h]); rel padded to 2304 with 0.
__global__ void rtT_kernel(const float* __restrict__ rtab, u16* __restrict__ rtT){
  int rel = blockIdx.x * 256 + threadIdx.x;
  int l = blockIdx.y;
  if(rel >= CRTP) return;
  const float* row = rtab + ((long)l*2212 + rel)*12;
  #pragma unroll
  for(int hh=0; hh<12; hh++){
    u16 v = 0;
    if(rel < 2212) v = f2b(row[hh]);
    rtT[((long)l*12 + hh)*CRTP + rel] = v;
  }
}

// ---------------- fused flash attention ----------------
// QBLK=64. K/V double-buffered, XOR-swizzled LDS via pre-swizzled source.
// rel-index computed arithmetically (q-side hoisted); bias via LDS rt-column.
__global__ __launch_bounds__(256) void attn_kernel(
    const u16* __restrict__ q, const u16* __restrict__ k,
    const u16* __restrict__ vt, const u16* __restrict__ rtT,
    u16* __restrict__ o_){
  __shared__ __align__(16) u16 lK[2][64*64];
  __shared__ __align__(16) u16 lV[2][64*64];
  __shared__ u16 pt[4][16*72];
  __shared__ __align__(16) u16 rtc[CRTP];
  const int tid = threadIdx.x, lane = tid & 63, wv = tid >> 6;
  const int i15 = lane & 15, g4 = lane >> 4;
  const int o = blockIdx.y * 10 + blockIdx.x;   // bh-major linear id (480 = 8*60)
  const int cm = xcd_chunk(o, 480);
  const int bh = cm / 10, qt = cm % 10;
  const int b = bh / CH, hh = bh % CH;
  const int qrow0 = qt*64 + wv*16;
  const u16* qp = q + ((long)bh*CN + qrow0 + i15)*CHD + g4*8;
  u16x8 qa0 = *reinterpret_cast<const u16x8*>(qp);
  u16x8 qa1 = *reinterpret_cast<const u16x8*>(qp + 32);
  const u16* kbase = k + (long)bh*CN*CHD;
  const u16* vbase = vt + (long)bh*CHD*CVP;

  for(int i = tid; i < CRTP/8; i += 256)
    *reinterpret_cast<u16x8*>(&rtc[i*8]) = *reinterpret_cast<const u16x8*>(rtT + (long)hh*CRTP + i*8);
  __syncthreads();

  int qbase[4];
  bool qz[4];
  #pragma unroll
  for(int r=0;r<4;r++){
    int qr = qrow0 + g4*4 + r; if(qr > 576) qr = 576;
    qz[r] = (qr == 0);
    int pq = qr - 1; if(pq < 0) pq = 0;
    int iq = pq / 24, jq = pq - iq*24;
    qbase[r] = (iq + 23)*47 + (jq + 23);
  }

  const int srow = wv*16 + (lane>>3);
  const int scol = (((lane&7) ^ ((lane>>3)&7)))*8;
  const int sdst = wv*16*64;
  const int rsw = i15 & 7;

  f32x4 po[4];
  float m[4], l[4];
  #pragma unroll
  for(int i=0;i<4;i++){ po[i]=(f32x4){0,0,0,0}; m[i]=-3.0e38f; l[i]=0.0f; }

  auto STAGE = [&](int t, int buf){
    const int kv0 = t*64;
    const u16* ks = kbase + ((long)(kv0 + srow))*CHD + scol;
    const u16* vs = vbase + ((long)srow)*CVP + kv0 + scol;
    gl_lds16(ks,          &lK[buf][sdst]);
    gl_lds16(ks + 8*CHD,  &lK[buf][sdst + 8*64]);
    gl_lds16(vs,          &lV[buf][sdst]);
    gl_lds16(vs + 8*CVP,  &lV[buf][sdst + 8*64]);
  };

  STAGE(0, 0);
  for(int t=0;t<10;t++){
    const int kv0 = t*64;
    int idxr[4][4];
    #pragma unroll
    for(int fc=0;fc<4;fc++){
      int kvc = kv0 + fc*16 + i15; if(kvc > 576) kvc = 576;
      bool kz = (kvc == 0);
      int pk = kvc - 1; if(pk < 0) pk = 0;
      int ik = pk / 24, jk = pk - ik*24;
      int ksub = ik*47 + jk;
      #pragma unroll
      for(int r=0;r<4;r++){
        int idx = qbase[r] - ksub;
        if(qz[r]) idx = 2209;
        if(kz)    idx = qz[r] ? 2211 : 2210;
        idxr[fc][r] = idx;
      }
    }
    if(t+1 < 10){
      STAGE(t+1, (t+1)&1);
      asm volatile("s_waitcnt vmcnt(4) lgkmcnt(0)" ::: "memory");
    } else {
      asm volatile("s_waitcnt vmcnt(0) lgkmcnt(0)" ::: "memory");
    }
    __builtin_amdgcn_s_barrier();
    const int buf = t&1;
    f32x4 sa[4];
    __builtin_amdgcn_s_setprio(1);
    #pragma unroll
    for(int fc=0;fc<4;fc++){
      const int rb = (fc*16+i15)*64;
      u16x8 k0 = *reinterpret_cast<const u16x8*>(&lK[buf][rb + ((g4 ^ rsw)<<3)]);
      u16x8 k1 = *reinterpret_cast<const u16x8*>(&lK[buf][rb + (((4|g4) ^ rsw)<<3)]);
      f32x4 z = (f32x4){0,0,0,0};
      z = MFMA(qa0, k0, z);
      z = MFMA(qa1, k1, z);
      sa[fc] = z;
    }
    __builtin_amdgcn_s_setprio(0);
    float s[4][4];
    #pragma unroll
    for(int fc=0;fc<4;fc++){
      int kvc = kv0 + fc*16 + i15;
      bool valid = kvc < CN;
      #pragma unroll
      for(int r=0;r<4;r++){
        float bias = b2f(rtc[idxr[fc][r]]);
        s[fc][r] = valid ? (sa[fc][r] + bias) : -1e30f;
      }
    }
    float tm[4], ts[4], sc[4];
    #pragma unroll
    for(int r=0;r<4;r++)
      tm[r] = fmaxf(fmaxf(s[0][r],s[1][r]), fmaxf(s[2][r],s[3][r]));
    #pragma unroll
    for(int msk=1; msk<16; msk<<=1)
      #pragma unroll
      for(int r=0;r<4;r++)
        tm[r] = fmaxf(tm[r], __shfl_xor(tm[r], msk));
    #pragma unroll
    for(int r=0;r<4;r++){
      float mn = fmaxf(m[r], tm[r]);
      sc[r] = exp2f((m[r]-mn)*1.4426950408889634f);
      m[r] = mn;
      ts[r] = 0.f;
    }
    #pragma unroll
    for(int fc=0;fc<4;fc++)
      #pragma unroll
      for(int r=0;r<4;r++){
        float p = exp2f((s[fc][r]-m[r])*1.4426950408889634f);
        s[fc][r] = p; ts[r] += p;
      }
    #pragma unroll
    for(int msk=1; msk<16; msk<<=1)
      #pragma unroll
      for(int r=0;r<4;r++)
        ts[r] += __shfl_xor(ts[r], msk);
    #pragma unroll
    for(int r=0;r<4;r++) l[r] = l[r]*sc[r] + ts[r];
    #pragma unroll
    for(int d=0; d<4; d++)
      #pragma unroll
      for(int r=0;r<4;r++) po[d][r] *= sc[r];
    #pragma unroll
    for(int fc=0;fc<4;fc++)
      #pragma unroll
      for(int r=0;r<4;r++)
        pt[wv][(g4*4+r)*72 + fc*16 + i15] = f2b(s[fc][r]);
    u16x8 pa0 = *reinterpret_cast<const u16x8*>(&pt[wv][i15*72 + g4*8]);
    u16x8 pa1 = *reinterpret_cast<const u16x8*>(&pt[wv][i15*72 + 32 + g4*8]);
    __builtin_amdgcn_s_setprio(1);
    #pragma unroll
    for(int d=0; d<4; d++){
      const int rb = (d*16+i15)*64;
      u16x8 v0 = *reinterpret_cast<const u16x8*>(&lV[buf][rb + ((g4 ^ rsw)<<3)]);
      u16x8 v1 = *reinterpret_cast<const u16x8*>(&lV[buf][rb + (((4|g4) ^ rsw)<<3)]);
      po[d] = MFMA(pa0, v0, po[d]);
      po[d] = MFMA(pa1, v1, po[d]);
    }
    __builtin_amdgcn_s_setprio(0);
    __builtin_amdgcn_s_barrier();
  }
  #pragma unroll
  for(int d=0; d<4; d++)
    #pragma unroll
    for(int r=0;r<4;r++){
      int qr = qrow0 + g4*4 + r;
      if(qr < CN)
        o_[((long)(b*CN + qr))*CD + hh*CHD + d*16 + i15] = f2b(po[d][r] / l[r]);
    }
}

__global__ void pool_kernel(const float* __restrict__ h, float* __restrict__ pooled){
  int id = blockIdx.x * 256 + threadIdx.x;
  if(id >= CBATCH*CD) return;
  int b = id / CD, d = id % CD;
  const float* p = h + ((long)b*CN + 1)*CD + d;
  float s = 0.0f;
  for(int i=0;i<CNP;i++) s += p[(long)i*CD];
  pooled[id] = s * (1.0f/576.0f);
}

__global__ void head_kernel(const float* __restrict__ xn, const float* __restrict__ hw,
                            const float* __restrict__ hb, float* __restrict__ out){
  int nc = blockIdx.x;
  int tid = threadIdx.x;
  const float* wr = hw + (long)nc*CD;
  float w0 = wr[tid], w1 = wr[tid+256], w2 = wr[tid+512];
  __shared__ float red[4];
  for(int b=0;b<CBATCH;b++){
    const float* xr = xn + (long)b*CD;
    float s = w0*xr[tid] + w1*xr[tid+256] + w2*xr[tid+512];
    #pragma unroll
    for(int m=1;m<64;m<<=1) s += __shfl_xor(s, m);
    if((tid&63)==0) red[tid>>6] = s;
    __syncthreads();
    if(tid==0) out[b*1000 + nc] = red[0]+red[1]+red[2]+red[3] + hb[nc];
    __syncthreads();
  }
}

// ---------------- GEMM: 64x128 tile, 3-slot counted-vmcnt pipeline -----------
// LDS rows XOR-swizzled via pre-swizzled global source (2-way, free).
// setprio(1) around the MFMA cluster.

struct EpiArgs {
  float* hres;
  u16* outb;
  const float* bias;
  const float* pos;
  const float* qb;
  const float* vb;
  u16* q;
  u16* k;
  u16* vt;
  float* part;
};

enum { EPI_PATCH=0, EPI_QKV, EPI_GELU, EPI_PART };

template<int EPI>
__global__ __launch_bounds__(256,4) void gemm4(const u16* __restrict__ A, const u16* __restrict__ Bm,
    int M, int N, int K, int lda, int ldb, EpiArgs e){
  __shared__ __align__(16) u16 lA[3][64*32];
  __shared__ __align__(16) u16 lB[3][128*32];
  const int tid  = threadIdx.x;
  const int lane = tid & 63;
  const int wv   = tid >> 6;

  const int gx = gridDim.x, gy = gridDim.y;
  const int o = blockIdx.y * gx + blockIdx.x;
  const int cm = xcd_chunk(o, gx*gy);          // column-major tile index
  const int bn = (cm / gy) * 128;
  const int bm = (cm % gy) * 64;

  const int z  = blockIdx.z;
  A  += (long)z * K;
  Bm += (long)z * K;

  const int srow = wv*16 + (lane>>2);
  const int wsz = ((lane&3) ^ ((lane>>3)&3)) * 8;
  const u16* Asb = A  + (long)(bm + srow)*lda + wsz;
  const u16* Bsb = Bm + (long)(bn + srow)*ldb + wsz;
  const int ldst = wv*16*32;

  const int rbase = (wv>>1)*32;      // 0 or 32 within 64-row tile
  const int cbase = (wv&1)*64;       // 0 or 64 within 128-col tile
  const int i15 = lane & 15;
  const int k8off = (((lane>>4) ^ ((i15>>1)&3))) << 3;

  f32x4 acc[2][4];
  #pragma unroll
  for(int i=0;i<2;i++)
    #pragma unroll
    for(int j=0;j<4;j++)
      acc[i][j] = (f32x4){0.0f,0.0f,0.0f,0.0f};

  const int nkt = K >> 5;

  auto STAGE = [&](int kt, int slot){
    const u16* Ak = Asb + (long)kt*32;
    const u16* Bk = Bsb + (long)kt*32;
    gl_lds16(Ak,          &lA[slot][ldst]);
    gl_lds16(Bk,          &lB[slot][ldst]);
    gl_lds16(Bk + 64*ldb, &lB[slot][ldst + 64*32]);
  };

  STAGE(0, 0);
  if(nkt > 1) STAGE(1, 1);

  for(int kt=0; kt<nkt; kt++){
    if(kt+1 < nkt) asm volatile("s_waitcnt vmcnt(3) lgkmcnt(0)" ::: "memory");
    else           asm volatile("s_waitcnt vmcnt(0) lgkmcnt(0)" ::: "memory");
    __builtin_amdgcn_s_barrier();
    int nxt2 = kt + 2;
    if(nxt2 < nkt){ int sl = nxt2 % 3; STAGE(nxt2, sl); }
    const int cur = kt % 3;
    u16x8 af[2], bfr[4];
    #pragma unroll
    for(int f=0; f<2; f++)
      af[f]  = *reinterpret_cast<const u16x8*>(&lA[cur][(rbase + f*16 + i15)*32 + k8off]);
    #pragma unroll
    for(int f=0; f<4; f++)
      bfr[f] = *reinterpret_cast<const u16x8*>(&lB[cur][(cbase + f*16 + i15)*32 + k8off]);
    __builtin_amdgcn_s_setprio(1);
    #pragma unroll
    for(int fr=0; fr<2; fr++)
      #pragma unroll
      for(int fc=0; fc<4; fc++)
        acc[fr][fc] = MFMA(af[fr], bfr[fc], acc[fr][fc]);
    __builtin_amdgcn_s_setprio(0);
  }

  // epilogue: C/D layout col=lane&15, row=(lane>>4)*4+r
  #pragma unroll
  for(int fr=0; fr<2; fr++){
    #pragma unroll
    for(int fc=0; fc<4; fc++){
      #pragma unroll
      for(int r=0;r<4;r++){
        int row = bm + rbase + fr*16 + ((lane>>4)<<2) + r;
        int col = bn + cbase + fc*16 + i15;
        if(row >= M || col >= N) continue;
        float v = acc[fr][fc][r];
        if constexpr(EPI == EPI_PATCH){
          int b = row/576, p = row%576;
          e.hres[((long)b*CN + 1 + p)*CD + col] = v + e.bias[col] + e.pos[(long)(1+p)*CD + col];
        } else if constexpr(EPI == EPI_QKV){
          int b = row/CN, n = row%CN;
          if(col < 768){
            int hh = col>>6, d = col&63;
            e.q[(((long)(b*CH+hh))*CN + n)*CHD + d] = f2b((v + e.qb[col]) * 0.125f);
          } else if(col < 1536){
            int c2 = col-768; int hh = c2>>6, d = c2&63;
            e.k[(((long)(b*CH+hh))*CN + n)*CHD + d] = f2b(v);
          } else {
            int c2 = col-1536; int hh = c2>>6, d = c2&63;
            e.vt[(((long)(b*CH+hh))*CHD + d)*CVP + n] = f2b(v + e.vb[c2]);
          }
        } else if constexpr(EPI == EPI_GELU){
          float t = v + e.bias[col];
          e.outb[(long)row*N + col] = f2b(t * 0.5f * (1.0f + erff(t*0.70710678118f)));
        } else { // EPI_PART: f32 partial, bias added in resid_ln
          e.part[((long)z*CROWS + row)*CD + col] = v;
        }
      }
    }
  }
}

// ---------------- host ----------------

extern "C" void kernel_launch(void* const* d_in, const int* in_sizes, int n_in,
                              void* d_out, int out_size, void* d_ws, size_t ws_size,
                              hipStream_t stream){
  const float* x        = (const float*)d_in[0];
  const float* patch_w  = (const float*)d_in[1];
  const float* patch_b  = (const float*)d_in[2];
  const float* cls_tok  = (const float*)d_in[3];
  const float* pos_emb  = (const float*)d_in[4];
  const float* ln1_w    = (const float*)d_in[5];
  const float* ln1_b    = (const float*)d_in[6];
  const float* qkv_w    = (const float*)d_in[7];
  const float* q_bias   = (const float*)d_in[8];
  const float* v_bias   = (const float*)d_in[9];
  const float* proj_w   = (const float*)d_in[10];
  const float* proj_b   = (const float*)d_in[11];
  const float* ln2_w    = (const float*)d_in[12];
  const float* ln2_b    = (const float*)d_in[13];
  const float* fc1_w    = (const float*)d_in[14];
  const float* fc1_b    = (const float*)d_in[15];
  const float* fc2_w    = (const float*)d_in[16];
  const float* fc2_b    = (const float*)d_in[17];
  const float* rel_tab  = (const float*)d_in[18];
  const float* fcn_w    = (const float*)d_in[19];
  const float* fcn_b    = (const float*)d_in[20];
  const float* head_w   = (const float*)d_in[21];
  const float* head_b   = (const float*)d_in[22];
  float* out = (float*)d_out;
  char* ws = (char*)d_ws;

  size_t off = 0;
  auto alloc = [&](size_t bytes)->size_t{
    size_t o = off; off += (bytes + 255) & ~(size_t)255; return o;
  };
  const size_t OFF_H    = alloc((size_t)CROWS*CD*4);            // f32 residual
  const size_t OFF_Y    = alloc((size_t)CROWSP*CD*2);           // bf16 LN out
  const size_t OFF_Q    = alloc(((size_t)CBH*CN + 128)*CHD*2);
  const size_t OFF_K    = alloc(((size_t)CBH*CN + 128)*CHD*2);
  const size_t OFF_VT   = alloc((size_t)CBH*CHD*CVP*2);
  const size_t OFF_O    = alloc((size_t)CROWSP*CD*2);
  const size_t OFF_HID  = alloc((size_t)CROWSP*CMLP*2);         // also im2col A
  const size_t OFF_PART = alloc((size_t)4*CROWS*CD*4);          // split-K partials
  const size_t OFF_RTT  = alloc((size_t)CL*12*CRTP*2);          // rt columns (637 KB)
  const size_t OFF_WP0  = alloc((size_t)768*768*2);
  const size_t OFF_WQA  = alloc((size_t)CL*2304*768*2);
  const size_t OFF_WPA  = alloc((size_t)CL*768*768*2);
  const size_t OFF_W1A  = alloc((size_t)CL*3072*768*2);
  const size_t OFF_W2A  = alloc((size_t)CL*768*3072*2);
  const size_t OFF_PL   = alloc((size_t)CBATCH*CD*4);
  const size_t OFF_NM   = alloc((size_t)CBATCH*CD*4);
  (void)ws_size; (void)in_sizes; (void)n_in; (void)out_size;

  float* h      = (float*)(ws + OFF_H);
  u16*   y      = (u16*)(ws + OFF_Y);
  u16*   qb_    = (u16*)(ws + OFF_Q);
  u16*   kb_    = (u16*)(ws + OFF_K);
  u16*   vt_    = (u16*)(ws + OFF_VT);
  u16*   o_     = (u16*)(ws + OFF_O);
  u16*   hid    = (u16*)(ws + OFF_HID);
  float* part   = (float*)(ws + OFF_PART);
  u16*   rtT    = (u16*)(ws + OFF_RTT);
  u16*   wp0    = (u16*)(ws + OFF_WP0);
  u16*   wqA    = (u16*)(ws + OFF_WQA);
  u16*   wpA    = (u16*)(ws + OFF_WPA);
  u16*   w1A    = (u16*)(ws + OFF_W1A);
  u16*   w2A    = (u16*)(ws + OFF_W2A);
  float* pooled = (float*)(ws + OFF_PL);
  float* normed = (float*)(ws + OFF_NM);

  auto cvt = [&](const float* src, u16* dst, long n){
    cvt_kernel<<<dim3((unsigned)((n/4 + 255)/256)), dim3(256), 0, stream>>>(src, dst, (int)n);
  };

  // ---- upfront ----
  {
    int n = CBH*CHD*CVP;
    zero_kernel<<<dim3((n/8 + 255)/256), dim3(256), 0, stream>>>(vt_, n);
  }
  im2col_kernel<<<dim3((2304*768 + 255)/256), dim3(256), 0, stream>>>(x, hid);
  cvt(patch_w, wp0, 768*768);
  cvt(qkv_w,  wqA, (long)CL*2304*768);
  cvt(proj_w, wpA, (long)CL*768*768);
  cvt(fc1_w,  w1A, (long)CL*3072*768);
  cvt(fc2_w,  w2A, (long)CL*768*3072);
  rtT_kernel<<<dim3(CRTP/256, CL), dim3(256), 0, stream>>>(rel_tab, rtT);

  // ---- patch embed ----
  {
    EpiArgs e{}; e.hres = h; e.bias = patch_b; e.pos = pos_emb;
    gemm4<EPI_PATCH><<<dim3(6,36,1), dim3(256), 0, stream>>>(
        hid, wp0, 2304, 768, 768, 768, 768, e);
  }
  clspos_kernel<<<dim3(12), dim3(256), 0, stream>>>(cls_tok, pos_emb, h);

  // layer-0 LN1 (no pending partials)
  ln_kernel<true><<<dim3(CROWS), dim3(256), 0, stream>>>(
      h, ln1_w, ln1_b, y, nullptr);

  // ---- layers ----
  for(int l=0; l<CL; l++){
    { // qkv
      EpiArgs e{}; e.qb = q_bias + l*CD; e.vb = v_bias + l*CD;
      e.q = qb_; e.k = kb_; e.vt = vt_;
      gemm4<EPI_QKV><<<dim3(18,CMT,1), dim3(256), 0, stream>>>(
          y, wqA + (long)l*2304*768, CROWS, 2304, 768, 768, 768, e);
    }
    attn_kernel<<<dim3(10, CBH), dim3(256), 0, stream>>>(
        qb_, kb_, vt_, rtT + (long)l*12*CRTP, o_);
    { // proj partials: split-K=2, K'=384
      EpiArgs e{}; e.part = part;
      gemm4<EPI_PART><<<dim3(6,CMT,CSKP), dim3(256), 0, stream>>>(
          o_, wpA + (long)l*768*768, CROWS, 768, 768/CSKP, 768, 768, e);
    }
    // h += proj + pb ; y = LN2(h)
    resid_ln_kernel<true,CSKP><<<dim3(CROWS), dim3(256), 0, stream>>>(
        h, part, proj_b + l*CD, ln2_w + l*CD, ln2_b + l*CD, y);
    { // hid = gelu(y fc1^T + b1)
      EpiArgs e{}; e.outb = hid; e.bias = fc1_b + l*CMLP;
      gemm4<EPI_GELU><<<dim3(24,CMT,1), dim3(256), 0, stream>>>(
          y, w1A + (long)l*3072*768, CROWS, 3072, 768, 768, 768, e);
    }
    { // fc2 partials: split-K=2, K'=1536
      EpiArgs e{}; e.part = part;
      gemm4<EPI_PART><<<dim3(6,CMT,CSKF), dim3(256), 0, stream>>>(
          hid, w2A + (long)l*768*3072, CROWS, 768, 3072/CSKF, 3072, 3072, e);
    }
    if(l+1 < CL){
      // h += fc2 + b2 ; y = LN1_{l+1}(h)
      resid_ln_kernel<true,CSKF><<<dim3(CROWS), dim3(256), 0, stream>>>(
          h, part, fc2_b + l*CD, ln1_w + (l+1)*CD, ln1_b + (l+1)*CD, y);
    } else {
      resid_ln_kernel<false,CSKF><<<dim3(CROWS), dim3(256), 0, stream>>>(
          h, part, fc2_b + l*CD, nullptr, nullptr, nullptr);
    }
  }

  // ---- pool + fc_norm + head ----
  pool_kernel<<<dim3(12), dim3(256), 0, stream>>>(h, pooled);
  ln_kernel<false><<<dim3(CBATCH), dim3(256), 0, stream>>>(
      pooled, fcn_w, fcn_b, nullptr, normed);
  head_kernel<<<dim3(1000), dim3(256), 0, stream>>>(normed, head_w, head_b, out);
}